// Round 13
// baseline (456.302 us; speedup 1.0000x reference)
//
#include <hip/hip_runtime.h>
#include <hip/hip_cooperative_groups.h>

namespace cg = cooperative_groups;

// PointNet++ set abstraction: ball query (first-16-by-index within r=0.5) +
// gather + rel-coords/feat concat + 2-layer MLP (leaky 0.1) + max-pool.
// B=4, N=16384, M=4096, K=16.
//
// Round 13: ONE cooperative kernel (zero -> pack/hist/classify -> alloc ->
// scatter -> persistent main). Kills ~15us of graph-node gaps + memset node.
// Grid stores only points with sq >= 2.0 (straggler balls have sq >= 2.25;
// 0.25 margin vs ~1e-7 rounding -> exact). P4 = verbatim r12 main body as a
// 4-groups-per-block persistent loop; weights staged once per block.
// Fallback: if hipLaunchCooperativeKernel errors, run the proven r12 chain.

constexpr int N_PTS = 16384;
constexpr int M_Q   = 4096;
constexpr int KNN   = 16;
constexpr int TOTAL_Q = 4 * M_Q;     // 16384
constexpr int TOTAL_P = 4 * N_PTS;   // 65536
constexpr int GDIM   = 24;
constexpr int CELLS  = 4 * GDIM * GDIM * GDIM;  // 55296
constexpr int HCAP   = 256;
constexpr int NBLK   = 1024;         // coop grid (4 blocks/CU guaranteed)

// ---- ws layout (bytes) ----
constexpr size_t WS_PKX  = 0;                       // float4[65536]  1MB
constexpr size_t WS_SPX  = 1048576;                 // sorted float4  1MB
constexpr size_t WS_SIX  = 2097152;                 // sorted idx     256KB
constexpr size_t WS_OFF  = 2359296;                 // offs int[55296]
constexpr size_t WS_HIST = 2580480;                 // hist int[55296]
constexpr size_t WS_CNTS = 2801664;                 // int[16]
constexpr size_t WS_BKT  = 2801728;                 // 4 x int[16384]
constexpr size_t WS_SLST = 3063872;                 // int[16384]
constexpr size_t WS_NEED_GRID = 3129408;

__device__ __forceinline__ int cellOf(float v) {
    int c = (int)floorf(v * 2.0f) + 12;
    return c < 0 ? 0 : (c > GDIM - 1 ? GDIM - 1 : c);
}

// ---------------- scan macros (round-6 proven) ----------------
#define LOAD8(R, P, P2)                                          \
    {                                                            \
        _Pragma("unroll")                                        \
        for (int j = 0; j < 4; ++j) R[j] = (P)[j * 64];          \
        _Pragma("unroll")                                        \
        for (int j = 0; j < 4; ++j) R[4 + j] = (P2)[j * 64];     \
    }

#define PROC8(R, CB)                                                          \
    {                                                                         \
        _Pragma("unroll")                                                     \
        for (int j = 0; j < 8; ++j) {                                         \
            float dot = __fmul_rn(qx, R[j].x);                                \
            dot = __builtin_fmaf(qy, R[j].y, dot);                            \
            dot = __builtin_fmaf(qz, R[j].z, dot);                            \
            const float d2 = __fsub_rn(__fadd_rn(sqq, R[j].w),                \
                                       __fmul_rn(2.0f, dot));                 \
            const bool hit = (d2 <= 0.25f);                                   \
            const unsigned long long mk = __ballot(hit);                      \
            if (hit) {                                                        \
                const int pos = count + __popcll(mk & lt_mask);               \
                if (pos < KNN) sNbr[wave][pos] = (CB) + j * 64 + lane;        \
            }                                                                 \
            count += (int)__popcll(mk);                                       \
        }                                                                     \
    }

#define ACC8(A, V, WA, WB)                                                    \
    A[0] += (V) * (WA).x; A[1] += (V) * (WA).y;                               \
    A[2] += (V) * (WA).z; A[3] += (V) * (WA).w;                               \
    A[4] += (V) * (WB).x; A[5] += (V) * (WB).y;                               \
    A[6] += (V) * (WB).z; A[7] += (V) * (WB).w;

#define COMP(v, j) ((j) == 0 ? (v).x : (j) == 1 ? (v).y : (j) == 2 ? (v).z : (v).w)

// ================== THE cooperative all-in-one kernel ==================
__global__ __launch_bounds__(256, 4) void pe_coop_kernel(
    const float* __restrict__ xyz, const float* __restrict__ feat,
    const int*   __restrict__ fps,
    const float* __restrict__ W1, const float* __restrict__ b1,
    const float* __restrict__ W2, const float* __restrict__ b2,
    float* __restrict__ out,
    float4* __restrict__ pkX, float4* __restrict__ spX, int* __restrict__ sIx,
    int* __restrict__ offs, int* __restrict__ hist, int* __restrict__ cnts,
    int* __restrict__ bkt, int* __restrict__ sLst)
{
    cg::grid_group gg = cg::this_grid();

    __shared__ __align__(16) float sW1[192];
    __shared__ __align__(16) float sW2[1024];
    __shared__ float sb1[32];
    __shared__ float sb2[32];
    __shared__ int   sNbr[4][KNN];
    __shared__ int   sQ[4];
    __shared__ int   sBase;
    __shared__ __align__(16) float sUni[4][576];   // P2 scratch / hits / h1

    const int tid  = threadIdx.x;
    const int bid  = blockIdx.x;
    const int gthread = bid * 256 + tid;
    const int wave = tid >> 6;
    const int lane = tid & 63;
    const unsigned long long lt_mask = (1ull << lane) - 1ull;

    // stage weights once per block (distinct LDS from sUni)
    if (tid < 192) sW1[tid] = W1[tid];
    for (int i = tid; i < 1024; i += 256) sW2[i] = W2[i];
    if (tid < 32) { sb1[tid] = b1[tid]; sb2[tid] = b2[tid]; }

    // ---- P0: zero hist + cnts ----
    for (int i = gthread; i < CELLS + 16; i += NBLK * 256) {
        if (i < CELLS) hist[i] = 0;
        else cnts[i - CELLS] = 0;
    }
    gg.sync();

    // ---- P1: pack + hist (sq>=2 only) + classify ----
    {
        const int i = gthread;
        if (i < TOTAL_P) {
            const float x = xyz[i * 3 + 0], y = xyz[i * 3 + 1], z = xyz[i * 3 + 2];
            const float sq = __fadd_rn(__fadd_rn(__fmul_rn(x, x), __fmul_rn(y, y)),
                                       __fmul_rn(z, z));
            pkX[i] = make_float4(x, y, z, sq);
            if (sq >= 2.0f) {   // straggler balls only touch sq >= 2.25
                const int b = i >> 14;
                const int cell = ((b * GDIM + cellOf(z)) * GDIM + cellOf(y)) * GDIM + cellOf(x);
                atomicAdd(&hist[cell], 1);
            }
        }
        if (i < TOTAL_Q) {
            const int b = i >> 12;
            const int pidx = fps[i];
            const size_t base3 = ((size_t)b * N_PTS + pidx) * 3;
            const float x = xyz[base3 + 0], y = xyz[base3 + 1], z = xyz[base3 + 2];
            const float s = __fadd_rn(__fadd_rn(__fmul_rn(x, x), __fmul_rn(y, y)),
                                      __fmul_rn(z, z));
            const bool isStrag = (s >= 4.0f);
            int key = (int)s;
            key = key > 3 ? 3 : key;

            {
                const unsigned long long mk = __ballot(isStrag);
                if (mk) {
                    int base = 0;
                    if (lane == 0) base = atomicAdd(&cnts[4], (int)__popcll(mk));
                    base = __shfl(base, 0, 64);
                    if (isStrag) sLst[base + __popcll(mk & lt_mask)] = i;
                }
            }
            #pragma unroll
            for (int bb = 0; bb < 4; ++bb) {
                const bool mine = (!isStrag) && (key == bb);
                const unsigned long long mk = __ballot(mine);
                if (mk) {
                    int base = 0;
                    if (lane == 0) base = atomicAdd(&cnts[bb], (int)__popcll(mk));
                    base = __shfl(base, 0, 64);
                    if (mine) bkt[bb * TOTAL_Q + base + __popcll(mk & lt_mask)] = i;
                }
            }
        }
    }
    gg.sync();

    // ---- P2: per-256-cell-chunk alloc (blocks 0..215) ----
    if (bid < CELLS / 256) {
        int* sS = (int*)sUni;
        const int cell = bid * 256 + tid;
        const int v = hist[cell];
        sS[tid] = v;
        __syncthreads();
        #pragma unroll
        for (int off = 1; off < 256; off <<= 1) {
            const int t = (tid >= off) ? sS[tid - off] : 0;
            __syncthreads();
            sS[tid] += t;
            __syncthreads();
        }
        if (tid == 255) sBase = atomicAdd(&cnts[8], sS[255]);
        __syncthreads();
        offs[cell] = sBase + sS[tid] - v;   // exclusive start
    }
    gg.sync();

    // ---- P3: scatter (sq>=2 only); offs: start -> end ----
    if (gthread < TOTAL_P) {
        const float4 p = pkX[gthread];
        if (p.w >= 2.0f) {
            const int b = gthread >> 14;
            const int cell = ((b * GDIM + cellOf(p.z)) * GDIM + cellOf(p.y)) * GDIM + cellOf(p.x);
            const int pos = atomicAdd(&offs[cell], 1);
            spX[pos] = p;
            sIx[pos] = gthread & (N_PTS - 1);
        }
    }
    gg.sync();
    __syncthreads();   // weights visible (belt & braces)

    // ---- P4: persistent main loop (verbatim r12 group body) ----
    int c[5];
    #pragma unroll
    for (int t = 0; t < 5; ++t) c[t] = cnts[t];
    const int nStrag = c[4];
    const int nStragBlk = (nStrag + 3) >> 2;
    const int cShort = c[0] + c[1] + c[2] + c[3];
    const int nGroups = nStragBlk + ((cShort + 3) >> 2);

    for (int g = bid; g < nGroups; g += NBLK) {
        int q = -1;
        bool isStrag = false;
        if (g < nStragBlk) {
            const int si = g * 4 + wave;
            if (si < nStrag) { q = sLst[si]; isStrag = true; }
        } else {
            const int w = (g - nStragBlk) * 4 + wave;
            int off = 0;
            #pragma unroll
            for (int bb = 3; bb >= 0; --bb) {
                const int cc = c[bb];
                const int idx = w - off;
                if (idx >= 0 && idx < cc) q = bkt[bb * TOTAL_Q + idx];
                off += cc;
            }
        }

        const int b = (q >= 0) ? (q >> 12) : 0;
        const float4* pX = pkX + (size_t)b * N_PTS;
        float qx = 0.f, qy = 0.f, qz = 0.f, sqq = 0.f;

        if (q >= 0) {
            const float4 Q = pX[fps[q]];
            qx = Q.x; qy = Q.y; qz = Q.z; sqq = Q.w;

            if (isStrag) {
                int* sList = (int*)sUni[wave];
                const float SL = 0.5f + 4e-4f;
                const int lx = cellOf(qx - SL), hx = cellOf(qx + SL);
                const int ly = cellOf(qy - SL), hy = cellOf(qy + SL);
                const int lz = cellOf(qz - SL), hz = cellOf(qz + SL);

                int H = 0;
                for (int cz = lz; cz <= hz; ++cz) {
                    for (int cy = ly; cy <= hy; ++cy) {
                        const int rowBase = ((b * GDIM + cz) * GDIM + cy) * GDIM;
                        const int ca = rowBase + lx, cb = rowBase + hx;
                        int sS0, sE0, sS1 = 0, sE1 = 0;
                        const int m = ((ca >> 8) + 1) << 8;
                        if (cb < m) {
                            sS0 = offs[ca] - hist[ca]; sE0 = offs[cb];
                        } else {
                            sS0 = offs[ca] - hist[ca]; sE0 = offs[m - 1];
                            sS1 = offs[m] - hist[m];   sE1 = offs[cb];
                        }
                        #pragma unroll
                        for (int sg = 0; sg < 2; ++sg) {
                            const int st = sg ? sS1 : sS0;
                            const int en = sg ? sE1 : sE0;
                            for (int i0 = st; i0 < en; i0 += 64) {
                                const int ii = i0 + lane;
                                bool hit = false; int oi = 0;
                                if (ii < en) {
                                    const float4 p = spX[ii];
                                    oi = sIx[ii];
                                    float dot = __fmul_rn(qx, p.x);
                                    dot = __builtin_fmaf(qy, p.y, dot);
                                    dot = __builtin_fmaf(qz, p.z, dot);
                                    const float d2 = __fsub_rn(__fadd_rn(sqq, p.w),
                                                               __fmul_rn(2.0f, dot));
                                    hit = (d2 <= 0.25f);
                                }
                                const unsigned long long mk = __ballot(hit);
                                if (hit) {
                                    const int pos = H + __popcll(mk & lt_mask);
                                    if (pos < HCAP) sList[pos] = oi;
                                }
                                H += (int)__popcll(mk);
                            }
                        }
                    }
                }
                if (H > HCAP) H = HCAP;

                int v0 = (lane < H)       ? sList[lane]       : 0x7fffffff;
                int v1 = (lane + 64 < H)  ? sList[lane + 64]  : 0x7fffffff;
                int v2 = (lane + 128 < H) ? sList[lane + 128] : 0x7fffffff;
                int v3 = (lane + 192 < H) ? sList[lane + 192] : 0x7fffffff;
                int myNbr = 0, first = 0;
                for (int r = 0; r < KNN; ++r) {
                    int m2 = min(min(v0, v1), min(v2, v3));
                    #pragma unroll
                    for (int d = 1; d < 64; d <<= 1) {
                        const int o = __shfl_xor(m2, d, 64);
                        m2 = o < m2 ? o : m2;
                    }
                    if (r == 0) first = m2;        // H >= 1 (query itself)
                    const int sel = (m2 == 0x7fffffff) ? first : m2;
                    if (lane == r) myNbr = sel;
                    if (v0 == m2) v0 = 0x7fffffff;
                    else if (v1 == m2) v1 = 0x7fffffff;
                    else if (v2 == m2) v2 = 0x7fffffff;
                    else if (v3 == m2) v3 = 0x7fffffff;
                }
                if (lane < KNN) sNbr[wave][lane] = myNbr;
            } else {
                int count = 0;
                {
                    const float4* pA  = pX + lane;
                    const float4* pA2 = pA + 256;
                    const float4* pB  = pA + 512;
                    const float4* pB2 = pA + 768;
                    float4 ra[8], rb[8];

                    LOAD8(ra, pA, pA2);
                    __builtin_amdgcn_sched_barrier(0);

                    for (int base = 0; base < N_PTS; base += 1024) {
                        LOAD8(rb, pB, pB2);
                        __builtin_amdgcn_sched_barrier(0);
                        PROC8(ra, base);
                        if (count >= KNN) break;    // wave-uniform
                        pA += 1024; pA2 += 1024;
                        if (base + 1024 < N_PTS) {
                            LOAD8(ra, pA, pA2);
                            __builtin_amdgcn_sched_barrier(0);
                        }
                        PROC8(rb, base + 512);
                        if (count >= KNN) break;
                        pB += 1024; pB2 += 1024;
                    }
                }
                if (count < KNN) {
                    const int first = sNbr[wave][0];   // count >= 1
                    if (lane >= count && lane < KNN) sNbr[wave][lane] = first;
                }
            }
        }

        // ---- h1 per wave -> sUni ----
        const int k  = lane >> 2;
        const int co = (lane & 3) * 8;
        if (q >= 0) {
            const int ni = sNbr[wave][k];
            const float4 gx = pX[ni];
            const size_t f3 = ((size_t)b * N_PTS + ni) * 3;
            const float in0 = gx.x - qx;
            const float in1 = gx.y - qy;
            const float in2 = gx.z - qz;
            const float in3 = feat[f3 + 0];
            const float in4 = feat[f3 + 1];
            const float in5 = feat[f3 + 2];

            float h1[8];
            #pragma unroll
            for (int i = 0; i < 8; ++i) {
                float a = sb1[co + i];
                a += in0 * sW1[0 * 32 + co + i];
                a += in1 * sW1[1 * 32 + co + i];
                a += in2 * sW1[2 * 32 + co + i];
                a += in3 * sW1[3 * 32 + co + i];
                a += in4 * sW1[4 * 32 + co + i];
                a += in5 * sW1[5 * 32 + co + i];
                h1[i] = (a >= 0.0f) ? a : 0.1f * a;
            }
            float* Hw = sUni[wave];
            *(float4*)&Hw[k * 36 + co]     = make_float4(h1[0], h1[1], h1[2], h1[3]);
            *(float4*)&Hw[k * 36 + co + 4] = make_float4(h1[4], h1[5], h1[6], h1[7]);
        }
        if (lane == 0) sQ[wave] = q;
        __syncthreads();

        // ---- h2: wave 0, one W2 sweep for 4 queries ----
        if (wave == 0) {
            const int q0 = sQ[0], q1 = sQ[1], q2 = sQ[2], q3 = sQ[3];
            float a0[8], a1[8], a2[8], a3[8];
            #pragma unroll
            for (int i = 0; i < 8; ++i) {
                const float bb2 = sb2[co + i];
                a0[i] = bb2; a1[i] = bb2; a2[i] = bb2; a3[i] = bb2;
            }

            #pragma unroll 2
            for (int rrb = 0; rrb < 8; ++rrb) {
                const float4 h0  = *(const float4*)&sUni[0][k * 36 + rrb * 4];
                const float4 h1v = *(const float4*)&sUni[1][k * 36 + rrb * 4];
                const float4 h2v = *(const float4*)&sUni[2][k * 36 + rrb * 4];
                const float4 h3v = *(const float4*)&sUni[3][k * 36 + rrb * 4];
                #pragma unroll
                for (int j = 0; j < 4; ++j) {
                    const int rr = rrb * 4 + j;
                    const float4 wa = *(const float4*)&sW2[rr * 32 + co];
                    const float4 wb = *(const float4*)&sW2[rr * 32 + co + 4];
                    const float x0 = COMP(h0, j), x1 = COMP(h1v, j);
                    const float x2 = COMP(h2v, j), x3 = COMP(h3v, j);
                    ACC8(a0, x0, wa, wb);
                    ACC8(a1, x1, wa, wb);
                    ACC8(a2, x2, wa, wb);
                    ACC8(a3, x3, wa, wb);
                }
            }

            #define EPILOG(A, QV)                                             \
            if ((QV) >= 0) {                                                  \
                float h2o[8];                                                 \
                _Pragma("unroll")                                             \
                for (int i = 0; i < 8; ++i) {                                 \
                    float v = A[i];                                           \
                    v = (v >= 0.0f) ? v : 0.1f * v;                           \
                    v = fmaxf(v, __shfl_xor(v, 4, 64));                       \
                    v = fmaxf(v, __shfl_xor(v, 8, 64));                       \
                    v = fmaxf(v, __shfl_xor(v, 16, 64));                      \
                    v = fmaxf(v, __shfl_xor(v, 32, 64));                      \
                    h2o[i] = v;                                               \
                }                                                             \
                if (k == 0) {                                                 \
                    float* op = out + (size_t)(QV) * 32 + co;                 \
                    _Pragma("unroll")                                         \
                    for (int i = 0; i < 8; ++i) op[i] = h2o[i];               \
                }                                                             \
            }
            EPILOG(a0, q0)
            EPILOG(a1, q1)
            EPILOG(a2, q2)
            EPILOG(a3, q3)
            #undef EPILOG
        }
        __syncthreads();   // protect sUni/sQ reuse next group
    }
}

// ================== r12 fallback chain (proven 88us) ==================
__global__ __launch_bounds__(256) void g_prep_kernel(
    const float* __restrict__ xyz, const int* __restrict__ fps,
    float4* __restrict__ pkX, int* __restrict__ hist,
    int* __restrict__ bkt, int* __restrict__ sLst, int* __restrict__ cnts)
{
    const int i = blockIdx.x * 256 + threadIdx.x;
    const int lane = threadIdx.x & 63;
    const unsigned long long lt_mask = (1ull << lane) - 1ull;

    if (i < TOTAL_P) {
        const float x = xyz[i * 3 + 0], y = xyz[i * 3 + 1], z = xyz[i * 3 + 2];
        const float sq = __fadd_rn(__fadd_rn(__fmul_rn(x, x), __fmul_rn(y, y)),
                                   __fmul_rn(z, z));
        pkX[i] = make_float4(x, y, z, sq);
        if (sq >= 2.0f) {
            const int b = i >> 14;
            const int cell = ((b * GDIM + cellOf(z)) * GDIM + cellOf(y)) * GDIM + cellOf(x);
            atomicAdd(&hist[cell], 1);
        }
    }

    if (i < TOTAL_Q) {
        const int b = i >> 12;
        const int pidx = fps[i];
        const size_t base3 = ((size_t)b * N_PTS + pidx) * 3;
        const float x = xyz[base3 + 0], y = xyz[base3 + 1], z = xyz[base3 + 2];
        const float s = __fadd_rn(__fadd_rn(__fmul_rn(x, x), __fmul_rn(y, y)),
                                  __fmul_rn(z, z));
        const bool isStrag = (s >= 4.0f);
        int key = (int)s;
        key = key > 3 ? 3 : key;

        {
            const unsigned long long mk = __ballot(isStrag);
            if (mk) {
                int base = 0;
                if (lane == 0) base = atomicAdd(&cnts[4], (int)__popcll(mk));
                base = __shfl(base, 0, 64);
                if (isStrag) sLst[base + __popcll(mk & lt_mask)] = i;
            }
        }
        #pragma unroll
        for (int bb = 0; bb < 4; ++bb) {
            const bool mine = (!isStrag) && (key == bb);
            const unsigned long long mk = __ballot(mine);
            if (mk) {
                int base = 0;
                if (lane == 0) base = atomicAdd(&cnts[bb], (int)__popcll(mk));
                base = __shfl(base, 0, 64);
                if (mine) bkt[bb * TOTAL_Q + base + __popcll(mk & lt_mask)] = i;
            }
        }
    }
}

__global__ __launch_bounds__(256) void g_alloc_kernel(
    const int* __restrict__ hist, int* __restrict__ offs, int* __restrict__ gTotal)
{
    __shared__ int sS[256];
    __shared__ int sBase;
    const int tid = threadIdx.x;
    const int cell = blockIdx.x * 256 + tid;
    const int v = hist[cell];
    sS[tid] = v;
    __syncthreads();
    #pragma unroll
    for (int off = 1; off < 256; off <<= 1) {
        const int t = (tid >= off) ? sS[tid - off] : 0;
        __syncthreads();
        sS[tid] += t;
        __syncthreads();
    }
    if (tid == 255) sBase = atomicAdd(gTotal, sS[255]);
    __syncthreads();
    offs[cell] = sBase + sS[tid] - v;
}

__global__ __launch_bounds__(256) void g_scatter_kernel(
    const float4* __restrict__ pkX, int* __restrict__ offs,
    float4* __restrict__ spX, int* __restrict__ sIx)
{
    const int i = blockIdx.x * 256 + threadIdx.x;
    if (i >= TOTAL_P) return;
    const float4 p = pkX[i];
    if (p.w < 2.0f) return;
    const int b = i >> 14;
    const int cell = ((b * GDIM + cellOf(p.z)) * GDIM + cellOf(p.y)) * GDIM + cellOf(p.x);
    const int pos = atomicAdd(&offs[cell], 1);
    spX[pos] = p;
    sIx[pos] = i & (N_PTS - 1);
}

__global__ __launch_bounds__(256) void pe_grid_main_kernel(
    const float4* __restrict__ pkX, const float* __restrict__ feat,
    const int*   __restrict__ fps,
    const float4* __restrict__ spX, const int* __restrict__ sIx,
    const int*   __restrict__ offs, const int* __restrict__ hist,
    const int*   __restrict__ bkt, const int* __restrict__ sLst,
    const int*   __restrict__ cnts,
    const float* __restrict__ W1, const float* __restrict__ b1,
    const float* __restrict__ W2, const float* __restrict__ b2,
    float* __restrict__ out)
{
    __shared__ __align__(16) float sW1[192];
    __shared__ __align__(16) float sW2[1024];
    __shared__ float sb1[32];
    __shared__ float sb2[32];
    __shared__ int   sNbr[4][KNN];
    __shared__ int   sQ[4];
    __shared__ __align__(16) float sUni[4][576];

    const int tid = threadIdx.x;
    if (tid < 192) sW1[tid] = W1[tid];
    for (int i = tid; i < 1024; i += 256) sW2[i] = W2[i];
    if (tid < 32) { sb1[tid] = b1[tid]; sb2[tid] = b2[tid]; }
    __syncthreads();

    const int wave = tid >> 6;
    const int lane = tid & 63;
    const unsigned long long lt_mask = (1ull << lane) - 1ull;

    int c[5];
    #pragma unroll
    for (int t = 0; t < 5; ++t) c[t] = cnts[t];
    const int nStrag = c[4];
    const int nStragBlk = (nStrag + 3) >> 2;
    const int cShort = c[0] + c[1] + c[2] + c[3];
    const int nBlocks = nStragBlk + ((cShort + 3) >> 2);
    const int bid = blockIdx.x;
    if (bid >= nBlocks) return;

    int q = -1;
    bool isStrag = false;
    if (bid < nStragBlk) {
        const int si = bid * 4 + wave;
        if (si < nStrag) { q = sLst[si]; isStrag = true; }
    } else {
        const int w = (bid - nStragBlk) * 4 + wave;
        int off = 0;
        #pragma unroll
        for (int bb = 3; bb >= 0; --bb) {
            const int cc = c[bb];
            const int idx = w - off;
            if (idx >= 0 && idx < cc) q = bkt[bb * TOTAL_Q + idx];
            off += cc;
        }
    }

    const int b = (q >= 0) ? (q >> 12) : 0;
    const float4* pX = pkX + (size_t)b * N_PTS;
    float qx = 0.f, qy = 0.f, qz = 0.f, sqq = 0.f;

    if (q >= 0) {
        const float4 Q = pX[fps[q]];
        qx = Q.x; qy = Q.y; qz = Q.z; sqq = Q.w;

        if (isStrag) {
            int* sList = (int*)sUni[wave];
            const float SL = 0.5f + 4e-4f;
            const int lx = cellOf(qx - SL), hx = cellOf(qx + SL);
            const int ly = cellOf(qy - SL), hy = cellOf(qy + SL);
            const int lz = cellOf(qz - SL), hz = cellOf(qz + SL);

            int H = 0;
            for (int cz = lz; cz <= hz; ++cz) {
                for (int cy = ly; cy <= hy; ++cy) {
                    const int rowBase = ((b * GDIM + cz) * GDIM + cy) * GDIM;
                    const int ca = rowBase + lx, cb = rowBase + hx;
                    int sS0, sE0, sS1 = 0, sE1 = 0;
                    const int m = ((ca >> 8) + 1) << 8;
                    if (cb < m) {
                        sS0 = offs[ca] - hist[ca]; sE0 = offs[cb];
                    } else {
                        sS0 = offs[ca] - hist[ca]; sE0 = offs[m - 1];
                        sS1 = offs[m] - hist[m];   sE1 = offs[cb];
                    }
                    #pragma unroll
                    for (int sg = 0; sg < 2; ++sg) {
                        const int st = sg ? sS1 : sS0;
                        const int en = sg ? sE1 : sE0;
                        for (int i0 = st; i0 < en; i0 += 64) {
                            const int ii = i0 + lane;
                            bool hit = false; int oi = 0;
                            if (ii < en) {
                                const float4 p = spX[ii];
                                oi = sIx[ii];
                                float dot = __fmul_rn(qx, p.x);
                                dot = __builtin_fmaf(qy, p.y, dot);
                                dot = __builtin_fmaf(qz, p.z, dot);
                                const float d2 = __fsub_rn(__fadd_rn(sqq, p.w),
                                                           __fmul_rn(2.0f, dot));
                                hit = (d2 <= 0.25f);
                            }
                            const unsigned long long mk = __ballot(hit);
                            if (hit) {
                                const int pos = H + __popcll(mk & lt_mask);
                                if (pos < HCAP) sList[pos] = oi;
                            }
                            H += (int)__popcll(mk);
                        }
                    }
                }
            }
            if (H > HCAP) H = HCAP;

            int v0 = (lane < H)       ? sList[lane]       : 0x7fffffff;
            int v1 = (lane + 64 < H)  ? sList[lane + 64]  : 0x7fffffff;
            int v2 = (lane + 128 < H) ? sList[lane + 128] : 0x7fffffff;
            int v3 = (lane + 192 < H) ? sList[lane + 192] : 0x7fffffff;
            int myNbr = 0, first = 0;
            for (int r = 0; r < KNN; ++r) {
                int m2 = min(min(v0, v1), min(v2, v3));
                #pragma unroll
                for (int d = 1; d < 64; d <<= 1) {
                    const int o = __shfl_xor(m2, d, 64);
                    m2 = o < m2 ? o : m2;
                }
                if (r == 0) first = m2;
                const int sel = (m2 == 0x7fffffff) ? first : m2;
                if (lane == r) myNbr = sel;
                if (v0 == m2) v0 = 0x7fffffff;
                else if (v1 == m2) v1 = 0x7fffffff;
                else if (v2 == m2) v2 = 0x7fffffff;
                else if (v3 == m2) v3 = 0x7fffffff;
            }
            if (lane < KNN) sNbr[wave][lane] = myNbr;
        } else {
            int count = 0;
            {
                const float4* pA  = pX + lane;
                const float4* pA2 = pA + 256;
                const float4* pB  = pA + 512;
                const float4* pB2 = pA + 768;
                float4 ra[8], rb[8];

                LOAD8(ra, pA, pA2);
                __builtin_amdgcn_sched_barrier(0);

                for (int base = 0; base < N_PTS; base += 1024) {
                    LOAD8(rb, pB, pB2);
                    __builtin_amdgcn_sched_barrier(0);
                    PROC8(ra, base);
                    if (count >= KNN) break;
                    pA += 1024; pA2 += 1024;
                    if (base + 1024 < N_PTS) {
                        LOAD8(ra, pA, pA2);
                        __builtin_amdgcn_sched_barrier(0);
                    }
                    PROC8(rb, base + 512);
                    if (count >= KNN) break;
                    pB += 1024; pB2 += 1024;
                }
            }
            if (count < KNN) {
                const int first = sNbr[wave][0];
                if (lane >= count && lane < KNN) sNbr[wave][lane] = first;
            }
        }
    }

    const int k  = lane >> 2;
    const int co = (lane & 3) * 8;

    if (q >= 0) {
        const int ni = sNbr[wave][k];
        const float4 gx = pX[ni];
        const size_t f3 = ((size_t)b * N_PTS + ni) * 3;
        const float in0 = gx.x - qx;
        const float in1 = gx.y - qy;
        const float in2 = gx.z - qz;
        const float in3 = feat[f3 + 0];
        const float in4 = feat[f3 + 1];
        const float in5 = feat[f3 + 2];

        float h1[8];
        #pragma unroll
        for (int i = 0; i < 8; ++i) {
            float a = sb1[co + i];
            a += in0 * sW1[0 * 32 + co + i];
            a += in1 * sW1[1 * 32 + co + i];
            a += in2 * sW1[2 * 32 + co + i];
            a += in3 * sW1[3 * 32 + co + i];
            a += in4 * sW1[4 * 32 + co + i];
            a += in5 * sW1[5 * 32 + co + i];
            h1[i] = (a >= 0.0f) ? a : 0.1f * a;
        }
        float* Hw = sUni[wave];
        *(float4*)&Hw[k * 36 + co]     = make_float4(h1[0], h1[1], h1[2], h1[3]);
        *(float4*)&Hw[k * 36 + co + 4] = make_float4(h1[4], h1[5], h1[6], h1[7]);
    }
    if (lane == 0) sQ[wave] = q;
    __syncthreads();
    if (wave != 0) return;

    const int q0 = sQ[0], q1 = sQ[1], q2 = sQ[2], q3 = sQ[3];
    float a0[8], a1[8], a2[8], a3[8];
    #pragma unroll
    for (int i = 0; i < 8; ++i) {
        const float bb2 = sb2[co + i];
        a0[i] = bb2; a1[i] = bb2; a2[i] = bb2; a3[i] = bb2;
    }

    #pragma unroll 2
    for (int rrb = 0; rrb < 8; ++rrb) {
        const float4 h0  = *(const float4*)&sUni[0][k * 36 + rrb * 4];
        const float4 h1v = *(const float4*)&sUni[1][k * 36 + rrb * 4];
        const float4 h2v = *(const float4*)&sUni[2][k * 36 + rrb * 4];
        const float4 h3v = *(const float4*)&sUni[3][k * 36 + rrb * 4];
        #pragma unroll
        for (int j = 0; j < 4; ++j) {
            const int rr = rrb * 4 + j;
            const float4 wa = *(const float4*)&sW2[rr * 32 + co];
            const float4 wb = *(const float4*)&sW2[rr * 32 + co + 4];
            const float x0 = COMP(h0, j), x1 = COMP(h1v, j);
            const float x2 = COMP(h2v, j), x3 = COMP(h3v, j);
            ACC8(a0, x0, wa, wb);
            ACC8(a1, x1, wa, wb);
            ACC8(a2, x2, wa, wb);
            ACC8(a3, x3, wa, wb);
        }
    }

    #define EPILOG(A, QV)                                                     \
    if ((QV) >= 0) {                                                          \
        float h2o[8];                                                         \
        _Pragma("unroll")                                                     \
        for (int i = 0; i < 8; ++i) {                                         \
            float v = A[i];                                                   \
            v = (v >= 0.0f) ? v : 0.1f * v;                                   \
            v = fmaxf(v, __shfl_xor(v, 4, 64));                               \
            v = fmaxf(v, __shfl_xor(v, 8, 64));                               \
            v = fmaxf(v, __shfl_xor(v, 16, 64));                              \
            v = fmaxf(v, __shfl_xor(v, 32, 64));                              \
            h2o[i] = v;                                                       \
        }                                                                     \
        if (k == 0) {                                                         \
            float* op = out + (size_t)(QV) * 32 + co;                         \
            _Pragma("unroll")                                                 \
            for (int i = 0; i < 8; ++i) op[i] = h2o[i];                       \
        }                                                                     \
    }
    EPILOG(a0, q0)
    EPILOG(a1, q1)
    EPILOG(a2, q2)
    EPILOG(a3, q3)
    #undef EPILOG
}

// ================== minimal r1 fallback (tiny ws) ==================
__global__ __launch_bounds__(256) void pe_flow_fused_kernel(
    const float* __restrict__ xyz, const float* __restrict__ feat,
    const int* __restrict__ fps,
    const float* __restrict__ W1, const float* __restrict__ b1,
    const float* __restrict__ W2, const float* __restrict__ b2,
    float* __restrict__ out)
{
    __shared__ float sW1[192];
    __shared__ float sW2[1024];
    __shared__ float sb1[32];
    __shared__ float sb2[32];
    __shared__ int   sNbr[4][KNN];

    const int tid = threadIdx.x;
    if (tid < 192) sW1[tid] = W1[tid];
    for (int i = tid; i < 1024; i += 256) sW2[i] = W2[i];
    if (tid < 32) { sb1[tid] = b1[tid]; sb2[tid] = b2[tid]; }
    __syncthreads();

    const int wave = tid >> 6;
    const int lane = tid & 63;
    const int q = blockIdx.x * 4 + wave;
    const int b = q >> 12;
    const int m = q & (M_Q - 1);

    const float* xb = xyz  + (size_t)b * N_PTS * 3;
    const float* fb = feat + (size_t)b * N_PTS * 3;

    const int pidx = fps[b * M_Q + m];
    const float qx = xb[pidx * 3 + 0];
    const float qy = xb[pidx * 3 + 1];
    const float qz = xb[pidx * 3 + 2];
    const float sq_q = __fadd_rn(__fadd_rn(__fmul_rn(qx, qx), __fmul_rn(qy, qy)),
                                 __fmul_rn(qz, qz));

    int count = 0;
    const unsigned long long lt_mask = (1ull << lane) - 1ull;
    for (int base = 0; base < N_PTS; base += 64) {
        const int i = base + lane;
        const float px = xb[i * 3 + 0];
        const float py = xb[i * 3 + 1];
        const float pz = xb[i * 3 + 2];
        const float sq_p = __fadd_rn(__fadd_rn(__fmul_rn(px, px), __fmul_rn(py, py)),
                                     __fmul_rn(pz, pz));
        float dot = __fmul_rn(qx, px);
        dot = __builtin_fmaf(qy, py, dot);
        dot = __builtin_fmaf(qz, pz, dot);
        const float d2 = __fsub_rn(__fadd_rn(sq_q, sq_p), __fmul_rn(2.0f, dot));
        const bool hit = (d2 <= 0.25f);
        const unsigned long long mk = __ballot(hit);
        if (hit) {
            const int pos = count + __popcll(mk & lt_mask);
            if (pos < KNN) sNbr[wave][pos] = i;
        }
        count += (int)__popcll(mk);
        if (count >= KNN) break;
    }
    if (count < KNN) {
        const int first = sNbr[wave][0];
        if (lane >= count && lane < KNN) sNbr[wave][lane] = first;
    }

    const int k = lane >> 2;
    const int co = (lane & 3) * 8;
    const int ni = sNbr[wave][k];

    const float in0 = xb[ni * 3 + 0] - qx;
    const float in1 = xb[ni * 3 + 1] - qy;
    const float in2 = xb[ni * 3 + 2] - qz;
    const float in3 = fb[ni * 3 + 0];
    const float in4 = fb[ni * 3 + 1];
    const float in5 = fb[ni * 3 + 2];

    float h1[8];
    #pragma unroll
    for (int i = 0; i < 8; ++i) {
        float a = sb1[co + i];
        a += in0 * sW1[0 * 32 + co + i];
        a += in1 * sW1[1 * 32 + co + i];
        a += in2 * sW1[2 * 32 + co + i];
        a += in3 * sW1[3 * 32 + co + i];
        a += in4 * sW1[4 * 32 + co + i];
        a += in5 * sW1[5 * 32 + co + i];
        h1[i] = (a >= 0.0f) ? a : 0.1f * a;
    }

    float h2[8];
    #pragma unroll
    for (int i = 0; i < 8; ++i) h2[i] = sb2[co + i];
    const int baseLane = lane & ~3;
    #pragma unroll
    for (int jj = 0; jj < 8; ++jj) {
        #pragma unroll
        for (int g = 0; g < 4; ++g) {
            const float v = __shfl(h1[jj], baseLane + g, 64);
            const int row = g * 8 + jj;
            #pragma unroll
            for (int i = 0; i < 8; ++i)
                h2[i] += v * sW2[row * 32 + co + i];
        }
    }

    #pragma unroll
    for (int i = 0; i < 8; ++i) {
        float v = h2[i];
        v = (v >= 0.0f) ? v : 0.1f * v;
        v = fmaxf(v, __shfl_xor(v, 4, 64));
        v = fmaxf(v, __shfl_xor(v, 8, 64));
        v = fmaxf(v, __shfl_xor(v, 16, 64));
        v = fmaxf(v, __shfl_xor(v, 32, 64));
        h2[i] = v;
    }

    if (k == 0) {
        float* op = out + (size_t)q * 32 + co;
        #pragma unroll
        for (int i = 0; i < 8; ++i) op[i] = h2[i];
    }
}

extern "C" void kernel_launch(void* const* d_in, const int* in_sizes, int n_in,
                              void* d_out, int out_size, void* d_ws, size_t ws_size,
                              hipStream_t stream) {
    const float* xyz  = (const float*)d_in[0];
    const float* feat = (const float*)d_in[1];
    const int*   fps  = (const int*)d_in[2];
    const float* W1   = (const float*)d_in[3];
    const float* b1   = (const float*)d_in[4];
    const float* W2   = (const float*)d_in[5];
    const float* b2   = (const float*)d_in[6];
    float* out = (float*)d_out;

    if (ws_size < WS_NEED_GRID) {
        pe_flow_fused_kernel<<<TOTAL_Q / 4, 256, 0, stream>>>(
            xyz, feat, fps, W1, b1, W2, b2, out);
        return;
    }

    char* ws = (char*)d_ws;
    float4* pkX = (float4*)(ws + WS_PKX);
    float4* spX = (float4*)(ws + WS_SPX);
    int* sIx    = (int*)(ws + WS_SIX);
    int* offs   = (int*)(ws + WS_OFF);
    int* hist   = (int*)(ws + WS_HIST);
    int* cnts   = (int*)(ws + WS_CNTS);
    int* bkt    = (int*)(ws + WS_BKT);
    int* sLst   = (int*)(ws + WS_SLST);

    // ---- preferred: single cooperative kernel ----
    {
        void* args[] = {
            (void*)&xyz, (void*)&feat, (void*)&fps,
            (void*)&W1, (void*)&b1, (void*)&W2, (void*)&b2, (void*)&out,
            (void*)&pkX, (void*)&spX, (void*)&sIx,
            (void*)&offs, (void*)&hist, (void*)&cnts,
            (void*)&bkt, (void*)&sLst
        };
        hipError_t e = hipLaunchCooperativeKernel(
            (const void*)pe_coop_kernel, dim3(NBLK), dim3(256), args, 0, stream);
        if (e == hipSuccess) return;
        // else fall through to the proven multi-kernel chain
    }

    // ---- fallback: r12 5-dispatch chain (proven) ----
    hipMemsetAsync(hist, 0, (size_t)CELLS * 4 + 64, stream);
    g_prep_kernel<<<TOTAL_P / 256, 256, 0, stream>>>(
        xyz, fps, pkX, hist, bkt, sLst, cnts);
    g_alloc_kernel<<<CELLS / 256, 256, 0, stream>>>(hist, offs, &cnts[8]);
    g_scatter_kernel<<<TOTAL_P / 256, 256, 0, stream>>>(pkX, offs, spX, sIx);
    pe_grid_main_kernel<<<TOTAL_Q / 4 + 2, 256, 0, stream>>>(
        pkX, feat, fps, spX, sIx, offs, hist, bkt, sLst, cnts,
        W1, b1, W2, b2, out);
}

// Round 14
// 84.727 us; speedup vs baseline: 5.3855x; 5.3855x over previous
//
#include <hip/hip_runtime.h>

// PointNet++ set abstraction: ball query (first-16-by-index within r=0.5) +
// gather + rel-coords/feat concat + 2-layer MLP (leaky 0.1) + max-pool.
// B=4, N=16384, M=4096, K=16.
//
// Round 14: compose the two proven winners, drop everything else.
//  - Structure: r6's 2-node chain (memset 64B + prep + main; pre ~6us).
//  - Scan: verbatim r6 (8-wide double-banked, 1024 pts/iter, early exit),
//    8-bucket descending-length order (longest scans dispatch first).
//  - MLP: verbatim r12 shared-W2 sweep (h1 per wave -> LDS; wave 0 does h2
//    for all 4 queries off ONE W2 read sweep). Isolated delta: -5.4us.
//  - Lessons: no coop/grid.sync (r13), no dynamic queues (r4), weights in
//    LDS (r7), no multi-query scan batching (r8), no segment split (r9),
//    literal-indexed regs only (r10), grid pre-chain too expensive (r11/12).

constexpr int N_PTS = 16384;
constexpr int M_Q   = 4096;
constexpr int KNN   = 16;
constexpr int TOTAL_Q = 4 * M_Q;     // 16384
constexpr int TOTAL_P = 4 * N_PTS;   // 65536
constexpr int NBKT   = 8;

// ---- ws layout ----
constexpr size_t WS_PKX  = 0;                                   // float4[65536] 1MB
constexpr size_t WS_BKT  = WS_PKX + (size_t)TOTAL_P * 16;       // 8 x int[16384]
constexpr size_t WS_CNTS = WS_BKT + (size_t)NBKT * TOTAL_Q * 4; // int[8]
constexpr size_t WS_NEED = WS_CNTS + 64;

// ------- pre-pass: pack points + 8 descending-length buckets -------
__global__ __launch_bounds__(256) void prep_kernel(
    const float* __restrict__ xyz, const int* __restrict__ fps,
    float4* __restrict__ pkX, int* __restrict__ bkt, int* __restrict__ cnts)
{
    const int i = blockIdx.x * 256 + threadIdx.x;
    const int lane = threadIdx.x & 63;
    const unsigned long long lt_mask = (1ull << lane) - 1ull;

    // pack points: {x,y,z,|p|^2} with the reference-exact sq expression
    if (i < TOTAL_P) {
        const float x = xyz[i * 3 + 0], y = xyz[i * 3 + 1], z = xyz[i * 3 + 2];
        const float sq = __fadd_rn(__fadd_rn(__fmul_rn(x, x), __fmul_rn(y, y)),
                                   __fmul_rn(z, z));
        pkX[i] = make_float4(x, y, z, sq);
    }

    // classify queries into 8 buckets by floor(|q|^2); scan len ~ e^{s/2}
    if (i < TOTAL_Q) {
        const int b = i >> 12;
        const int pidx = fps[i];
        const size_t base3 = ((size_t)b * N_PTS + pidx) * 3;
        const float x = xyz[base3 + 0], y = xyz[base3 + 1], z = xyz[base3 + 2];
        const float s = __fadd_rn(__fadd_rn(__fmul_rn(x, x), __fmul_rn(y, y)),
                                  __fmul_rn(z, z));
        int key = (int)s;
        key = key > NBKT - 1 ? NBKT - 1 : key;   // 0..7

        #pragma unroll
        for (int bb = 0; bb < NBKT; ++bb) {
            const bool mine = (key == bb);
            const unsigned long long mk = __ballot(mine);
            if (mk) {                                  // wave-aggregated
                int base = 0;
                if (lane == 0) base = atomicAdd(&cnts[bb], (int)__popcll(mk));
                base = __shfl(base, 0, 64);
                if (mine) bkt[bb * TOTAL_Q + base + __popcll(mk & lt_mask)] = i;
            }
        }
    }
}

// ---------------- scan macros (round-6 proven) ----------------
#define LOAD8(R, P, P2)                                          \
    {                                                            \
        _Pragma("unroll")                                        \
        for (int j = 0; j < 4; ++j) R[j] = (P)[j * 64];          \
        _Pragma("unroll")                                        \
        for (int j = 0; j < 4; ++j) R[4 + j] = (P2)[j * 64];     \
    }

#define PROC8(R, CB)                                                          \
    {                                                                         \
        _Pragma("unroll")                                                     \
        for (int j = 0; j < 8; ++j) {                                         \
            float dot = __fmul_rn(qx, R[j].x);                                \
            dot = __builtin_fmaf(qy, R[j].y, dot);                            \
            dot = __builtin_fmaf(qz, R[j].z, dot);                            \
            const float d2 = __fsub_rn(__fadd_rn(sqq, R[j].w),                \
                                       __fmul_rn(2.0f, dot));                 \
            const bool hit = (d2 <= 0.25f);                                   \
            const unsigned long long mk = __ballot(hit);                      \
            if (hit) {                                                        \
                const int pos = count + __popcll(mk & lt_mask);               \
                if (pos < KNN) sNbr[wave][pos] = (CB) + j * 64 + lane;        \
            }                                                                 \
            count += (int)__popcll(mk);                                       \
        }                                                                     \
    }

#define ACC8(A, V, WA, WB)                                                    \
    A[0] += (V) * (WA).x; A[1] += (V) * (WA).y;                               \
    A[2] += (V) * (WA).z; A[3] += (V) * (WA).w;                               \
    A[4] += (V) * (WB).x; A[5] += (V) * (WB).y;                               \
    A[6] += (V) * (WB).z; A[7] += (V) * (WB).w;

#define COMP(v, j) ((j) == 0 ? (v).x : (j) == 1 ? (v).y : (j) == 2 ? (v).z : (v).w)

// ---------------- main fused kernel ----------------
__global__ __launch_bounds__(256) void pe_flow_main_kernel(
    const float4* __restrict__ pkX, const float* __restrict__ feat,
    const int*   __restrict__ fps,
    const int*   __restrict__ bkt, const int* __restrict__ cnts,
    const float* __restrict__ W1, const float* __restrict__ b1,
    const float* __restrict__ W2, const float* __restrict__ b2,
    float* __restrict__ out)
{
    __shared__ __align__(16) float sW1[192];
    __shared__ __align__(16) float sW2[1024];
    __shared__ float sb1[32];
    __shared__ float sb2[32];
    __shared__ int   sNbr[4][KNN];
    __shared__ int   sQ[4];
    __shared__ __align__(16) float sUni[4][576];   // h1: [wave][k*36 + c]

    const int tid = threadIdx.x;
    if (tid < 192) sW1[tid] = W1[tid];
    for (int i = tid; i < 1024; i += 256) sW2[i] = W2[i];
    if (tid < 32) { sb1[tid] = b1[tid]; sb2[tid] = b2[tid]; }
    __syncthreads();

    const int wave = tid >> 6;
    const int lane = tid & 63;
    const unsigned long long lt_mask = (1ull << lane) - 1ull;

    // ---- select query: descending bucket order (longest scans first) ----
    const int w = blockIdx.x * 4 + wave;        // 0..16383, all valid
    int q = 0, off = 0;
    #pragma unroll
    for (int bb = NBKT - 1; bb >= 0; --bb) {
        const int c = cnts[bb];
        const int idx = w - off;
        if (idx >= 0 && idx < c) q = bkt[bb * TOTAL_Q + idx];
        off += c;
    }
    const int b = q >> 12;

    const float4* pX = pkX + (size_t)b * N_PTS;
    const int pidx = fps[q];
    const float4 Q = pX[pidx];
    const float qx = Q.x, qy = Q.y, qz = Q.z, sqq = Q.w;

    // ---- ball query: first 16 in-radius indices, ascending (r6 scan) ----
    int count = 0;
    {
        const float4* pA  = pX + lane;
        const float4* pA2 = pA + 256;
        const float4* pB  = pA + 512;
        const float4* pB2 = pA + 768;
        float4 ra[8], rb[8];

        LOAD8(ra, pA, pA2);
        __builtin_amdgcn_sched_barrier(0);

        for (int base = 0; base < N_PTS; base += 1024) {
            LOAD8(rb, pB, pB2);
            __builtin_amdgcn_sched_barrier(0);
            PROC8(ra, base);
            if (count >= KNN) break;            // wave-uniform
            pA += 1024; pA2 += 1024;
            if (base + 1024 < N_PTS) {
                LOAD8(ra, pA, pA2);
                __builtin_amdgcn_sched_barrier(0);
            }
            PROC8(rb, base + 512);
            if (count >= KNN) break;
            pB += 1024; pB2 += 1024;
        }
    }
    if (count < KNN) {
        const int first = sNbr[wave][0];   // count >= 1 (query point itself)
        if (lane >= count && lane < KNN) sNbr[wave][lane] = first;
    }

    // ---- h1 phase: per wave (r6 math), result -> sUni ----
    const int k  = lane >> 2;
    const int co = (lane & 3) * 8;
    {
        const int ni = sNbr[wave][k];
        const float4 gx = pX[ni];
        const size_t f3 = ((size_t)b * N_PTS + ni) * 3;
        const float in0 = gx.x - qx;
        const float in1 = gx.y - qy;
        const float in2 = gx.z - qz;
        const float in3 = feat[f3 + 0];
        const float in4 = feat[f3 + 1];
        const float in5 = feat[f3 + 2];

        float h1[8];
        #pragma unroll
        for (int i = 0; i < 8; ++i) {
            float a = sb1[co + i];
            a += in0 * sW1[0 * 32 + co + i];
            a += in1 * sW1[1 * 32 + co + i];
            a += in2 * sW1[2 * 32 + co + i];
            a += in3 * sW1[3 * 32 + co + i];
            a += in4 * sW1[4 * 32 + co + i];
            a += in5 * sW1[5 * 32 + co + i];
            h1[i] = (a >= 0.0f) ? a : 0.1f * a;
        }
        float* Hw = sUni[wave];                       // [k][36] padded rows
        *(float4*)&Hw[k * 36 + co]     = make_float4(h1[0], h1[1], h1[2], h1[3]);
        *(float4*)&Hw[k * 36 + co + 4] = make_float4(h1[4], h1[5], h1[6], h1[7]);
    }
    if (lane == 0) sQ[wave] = q;
    __syncthreads();
    if (wave != 0) return;

    // ---- h2 phase: wave 0, ONE W2 sweep for all 4 queries (r12 proven) ----
    const int q0 = sQ[0], q1 = sQ[1], q2 = sQ[2], q3 = sQ[3];
    float a0[8], a1[8], a2[8], a3[8];
    #pragma unroll
    for (int i = 0; i < 8; ++i) {
        const float bb2 = sb2[co + i];
        a0[i] = bb2; a1[i] = bb2; a2[i] = bb2; a3[i] = bb2;
    }

    #pragma unroll 2
    for (int rrb = 0; rrb < 8; ++rrb) {
        const float4 h0  = *(const float4*)&sUni[0][k * 36 + rrb * 4];
        const float4 h1v = *(const float4*)&sUni[1][k * 36 + rrb * 4];
        const float4 h2v = *(const float4*)&sUni[2][k * 36 + rrb * 4];
        const float4 h3v = *(const float4*)&sUni[3][k * 36 + rrb * 4];
        #pragma unroll
        for (int j = 0; j < 4; ++j) {
            const int rr = rrb * 4 + j;
            const float4 wa = *(const float4*)&sW2[rr * 32 + co];
            const float4 wb = *(const float4*)&sW2[rr * 32 + co + 4];
            const float x0 = COMP(h0, j), x1 = COMP(h1v, j);
            const float x2 = COMP(h2v, j), x3 = COMP(h3v, j);
            ACC8(a0, x0, wa, wb);
            ACC8(a1, x1, wa, wb);
            ACC8(a2, x2, wa, wb);
            ACC8(a3, x3, wa, wb);
        }
    }

    // ---- leaky + maxpool (k bits 2..5) + store, per query ----
    #define EPILOG(A, QV)                                                     \
    {                                                                         \
        float h2o[8];                                                         \
        _Pragma("unroll")                                                     \
        for (int i = 0; i < 8; ++i) {                                         \
            float v = A[i];                                                   \
            v = (v >= 0.0f) ? v : 0.1f * v;                                   \
            v = fmaxf(v, __shfl_xor(v, 4, 64));                               \
            v = fmaxf(v, __shfl_xor(v, 8, 64));                               \
            v = fmaxf(v, __shfl_xor(v, 16, 64));                              \
            v = fmaxf(v, __shfl_xor(v, 32, 64));                              \
            h2o[i] = v;                                                       \
        }                                                                     \
        if (k == 0) {                                                         \
            float* op = out + (size_t)(QV) * 32 + co;                         \
            _Pragma("unroll")                                                 \
            for (int i = 0; i < 8; ++i) op[i] = h2o[i];                       \
        }                                                                     \
    }
    EPILOG(a0, q0)
    EPILOG(a1, q1)
    EPILOG(a2, q2)
    EPILOG(a3, q3)
    #undef EPILOG
}

// ---------------- round-1 fallback (self-contained, proven PASS) ----------------
__global__ __launch_bounds__(256) void pe_flow_fused_kernel(
    const float* __restrict__ xyz, const float* __restrict__ feat,
    const int* __restrict__ fps,
    const float* __restrict__ W1, const float* __restrict__ b1,
    const float* __restrict__ W2, const float* __restrict__ b2,
    float* __restrict__ out)
{
    __shared__ float sW1[192];
    __shared__ float sW2[1024];
    __shared__ float sb1[32];
    __shared__ float sb2[32];
    __shared__ int   sNbr[4][KNN];

    const int tid = threadIdx.x;
    if (tid < 192) sW1[tid] = W1[tid];
    for (int i = tid; i < 1024; i += 256) sW2[i] = W2[i];
    if (tid < 32) { sb1[tid] = b1[tid]; sb2[tid] = b2[tid]; }
    __syncthreads();

    const int wave = tid >> 6;
    const int lane = tid & 63;
    const int q = blockIdx.x * 4 + wave;
    const int b = q >> 12;
    const int m = q & (M_Q - 1);

    const float* xb = xyz  + (size_t)b * N_PTS * 3;
    const float* fb = feat + (size_t)b * N_PTS * 3;

    const int pidx = fps[b * M_Q + m];
    const float qx = xb[pidx * 3 + 0];
    const float qy = xb[pidx * 3 + 1];
    const float qz = xb[pidx * 3 + 2];
    const float sq_q = __fadd_rn(__fadd_rn(__fmul_rn(qx, qx), __fmul_rn(qy, qy)),
                                 __fmul_rn(qz, qz));

    int count = 0;
    const unsigned long long lt_mask = (1ull << lane) - 1ull;
    for (int base = 0; base < N_PTS; base += 64) {
        const int i = base + lane;
        const float px = xb[i * 3 + 0];
        const float py = xb[i * 3 + 1];
        const float pz = xb[i * 3 + 2];
        const float sq_p = __fadd_rn(__fadd_rn(__fmul_rn(px, px), __fmul_rn(py, py)),
                                     __fmul_rn(pz, pz));
        float dot = __fmul_rn(qx, px);
        dot = __builtin_fmaf(qy, py, dot);
        dot = __builtin_fmaf(qz, pz, dot);
        const float d2 = __fsub_rn(__fadd_rn(sq_q, sq_p), __fmul_rn(2.0f, dot));
        const bool hit = (d2 <= 0.25f);
        const unsigned long long mk = __ballot(hit);
        if (hit) {
            const int pos = count + __popcll(mk & lt_mask);
            if (pos < KNN) sNbr[wave][pos] = i;
        }
        count += (int)__popcll(mk);
        if (count >= KNN) break;
    }
    if (count < KNN) {
        const int first = sNbr[wave][0];
        if (lane >= count && lane < KNN) sNbr[wave][lane] = first;
    }

    const int k = lane >> 2;
    const int co = (lane & 3) * 8;
    const int ni = sNbr[wave][k];

    const float in0 = xb[ni * 3 + 0] - qx;
    const float in1 = xb[ni * 3 + 1] - qy;
    const float in2 = xb[ni * 3 + 2] - qz;
    const float in3 = fb[ni * 3 + 0];
    const float in4 = fb[ni * 3 + 1];
    const float in5 = fb[ni * 3 + 2];

    float h1[8];
    #pragma unroll
    for (int i = 0; i < 8; ++i) {
        float a = sb1[co + i];
        a += in0 * sW1[0 * 32 + co + i];
        a += in1 * sW1[1 * 32 + co + i];
        a += in2 * sW1[2 * 32 + co + i];
        a += in3 * sW1[3 * 32 + co + i];
        a += in4 * sW1[4 * 32 + co + i];
        a += in5 * sW1[5 * 32 + co + i];
        h1[i] = (a >= 0.0f) ? a : 0.1f * a;
    }

    float h2[8];
    #pragma unroll
    for (int i = 0; i < 8; ++i) h2[i] = sb2[co + i];
    const int baseLane = lane & ~3;
    #pragma unroll
    for (int jj = 0; jj < 8; ++jj) {
        #pragma unroll
        for (int g = 0; g < 4; ++g) {
            const float v = __shfl(h1[jj], baseLane + g, 64);
            const int row = g * 8 + jj;
            #pragma unroll
            for (int i = 0; i < 8; ++i)
                h2[i] += v * sW2[row * 32 + co + i];
        }
    }

    #pragma unroll
    for (int i = 0; i < 8; ++i) {
        float v = h2[i];
        v = (v >= 0.0f) ? v : 0.1f * v;
        v = fmaxf(v, __shfl_xor(v, 4, 64));
        v = fmaxf(v, __shfl_xor(v, 8, 64));
        v = fmaxf(v, __shfl_xor(v, 16, 64));
        v = fmaxf(v, __shfl_xor(v, 32, 64));
        h2[i] = v;
    }

    if (k == 0) {
        float* op = out + (size_t)q * 32 + co;
        #pragma unroll
        for (int i = 0; i < 8; ++i) op[i] = h2[i];
    }
}

extern "C" void kernel_launch(void* const* d_in, const int* in_sizes, int n_in,
                              void* d_out, int out_size, void* d_ws, size_t ws_size,
                              hipStream_t stream) {
    const float* xyz  = (const float*)d_in[0];
    const float* feat = (const float*)d_in[1];
    const int*   fps  = (const int*)d_in[2];
    const float* W1   = (const float*)d_in[3];
    const float* b1   = (const float*)d_in[4];
    const float* W2   = (const float*)d_in[5];
    const float* b2   = (const float*)d_in[6];
    float* out = (float*)d_out;

    if (ws_size < WS_NEED) {
        // fallback: proven round-1 kernel, no workspace needed
        pe_flow_fused_kernel<<<TOTAL_Q / 4, 256, 0, stream>>>(
            xyz, feat, fps, W1, b1, W2, b2, out);
        return;
    }

    char* ws = (char*)d_ws;
    float4* pkX = (float4*)(ws + WS_PKX);
    int* bkt    = (int*)(ws + WS_BKT);
    int* cnts   = (int*)(ws + WS_CNTS);

    hipMemsetAsync(cnts, 0, 64, stream);
    prep_kernel<<<TOTAL_P / 256, 256, 0, stream>>>(xyz, fps, pkX, bkt, cnts);
    pe_flow_main_kernel<<<TOTAL_Q / 4, 256, 0, stream>>>(
        pkX, feat, fps, bkt, cnts, W1, b1, W2, b2, out);
}